// Round 2
// baseline (563.937 us; speedup 1.0000x reference)
//
#include <hip/hip_runtime.h>
#include <hip/hip_bf16.h>

#define H 8
#define N 384
#define D 32
#define CIN 256
#define SCALER 0.17677669529663687f
#define EPS 1e-9f

// workspace float offsets
#define PROJ_OFF 0u              // 5*H*N*D = 491520 floats: a,b,c,vj,vk as [5][H][N][D]
#define S_OFF    491520u         // 3*H*N*N = 3538944 floats: X,Y,Z raw/exp'd [t][h][r][c]
#define YT_OFF   4030464u        // H*N*N: exp'd Y transposed [h][i][k]
#define MX_OFF   5210112u        // 8
#define MY_OFF   5210120u        // H*N
#define MZ_OFF   5213192u        // H*N
#define NUM_OFF  5216264u        // H*N*D
#define DEN_OFF  5314568u        // H*N

// ---------------- K1: projection GEMM  wx[n,m] = sum_k hs[n,k]*W[m,k] ----------------
__global__ __launch_bounds__(256) void proj_kernel(const float* __restrict__ hs,
                                                   const float* __restrict__ W,
                                                   float* __restrict__ proj) {
    __shared__ float hs_s[64][68];
    __shared__ float w_s[64][68];
    const int tid = threadIdx.x;
    const int tx = tid & 15, ty = tid >> 4;
    const int m0 = blockIdx.x * 64, n0 = blockIdx.y * 64;
    float acc[4][4] = {};
    for (int k0 = 0; k0 < CIN; k0 += 64) {
        __syncthreads();
#pragma unroll
        for (int rep = 0; rep < 4; ++rep) {
            int lin = rep * 1024 + tid * 4;
            int rl = lin >> 6, kl = lin & 63;
            float4 hv = *(const float4*)&hs[(n0 + rl) * CIN + k0 + kl];
            hs_s[kl + 0][rl] = hv.x; hs_s[kl + 1][rl] = hv.y;
            hs_s[kl + 2][rl] = hv.z; hs_s[kl + 3][rl] = hv.w;
            float4 wv = *(const float4*)&W[(m0 + rl) * CIN + k0 + kl];
            w_s[kl + 0][rl] = wv.x; w_s[kl + 1][rl] = wv.y;
            w_s[kl + 2][rl] = wv.z; w_s[kl + 3][rl] = wv.w;
        }
        __syncthreads();
#pragma unroll 16
        for (int kk = 0; kk < 64; ++kk) {
            float4 a4 = *(const float4*)&hs_s[kk][ty * 4];
            float4 b4 = *(const float4*)&w_s[kk][tx * 4];
            float av[4] = {a4.x, a4.y, a4.z, a4.w};
            float bv[4] = {b4.x, b4.y, b4.z, b4.w};
#pragma unroll
            for (int a_ = 0; a_ < 4; ++a_) {
#pragma unroll
                for (int b_ = 0; b_ < 4; ++b_) {
                    acc[a_][b_] = fmaf(av[a_], bv[b_], acc[a_][b_]);
                }
            }
        }
    }
#pragma unroll
    for (int a_ = 0; a_ < 4; ++a_) {
        int n = n0 + ty * 4 + a_;
#pragma unroll
        for (int b_ = 0; b_ < 4; ++b_) {
            int m = m0 + tx * 4 + b_;
            int s = m >> 8, hh = (m >> 5) & 7, d = m & 31;
            proj[s * (H * N * D) + hh * (N * D) + n * D + d] = acc[a_][b_];
        }
    }
}

// ---------------- K2: scores  S[t][h][r][c] = SCALER * dot(L[r,:], R[c,:]) ----------------
// t=0: X[j,k] = b.c   t=1: Y[k,i] = c.a   t=2: Z[i,j] = a.b
__global__ __launch_bounds__(256) void scores_kernel(const float* __restrict__ proj,
                                                     float* __restrict__ S) {
    __shared__ float LsT[32][68];
    __shared__ float RsT[32][68];
    const int tid = threadIdx.x, tx = tid & 15, ty = tid >> 4;
    const int r0 = blockIdx.x * 64;
    const int h = blockIdx.y;
    const int t = blockIdx.z;
    const int Lidx = (t == 0) ? 1 : (t == 1 ? 2 : 0);
    const int Ridx = (t == 0) ? 2 : (t == 1 ? 0 : 1);
    const float* Lp = proj + Lidx * (H * N * D) + h * (N * D);
    const float* Rp = proj + Ridx * (H * N * D) + h * (N * D);
    float* Sp = S + t * (H * N * N) + h * (N * N);
    {
        int i = tid >> 2, d8 = (tid & 3) * 8;
        float4 v0 = *(const float4*)&Lp[(r0 + i) * D + d8];
        float4 v1 = *(const float4*)&Lp[(r0 + i) * D + d8 + 4];
        LsT[d8 + 0][i] = v0.x; LsT[d8 + 1][i] = v0.y; LsT[d8 + 2][i] = v0.z; LsT[d8 + 3][i] = v0.w;
        LsT[d8 + 4][i] = v1.x; LsT[d8 + 5][i] = v1.y; LsT[d8 + 6][i] = v1.z; LsT[d8 + 7][i] = v1.w;
    }
    for (int c0 = 0; c0 < N; c0 += 64) {
        __syncthreads();
        {
            int i = tid >> 2, d8 = (tid & 3) * 8;
            float4 v0 = *(const float4*)&Rp[(c0 + i) * D + d8];
            float4 v1 = *(const float4*)&Rp[(c0 + i) * D + d8 + 4];
            RsT[d8 + 0][i] = v0.x; RsT[d8 + 1][i] = v0.y; RsT[d8 + 2][i] = v0.z; RsT[d8 + 3][i] = v0.w;
            RsT[d8 + 4][i] = v1.x; RsT[d8 + 5][i] = v1.y; RsT[d8 + 6][i] = v1.z; RsT[d8 + 7][i] = v1.w;
        }
        __syncthreads();
        float acc[4][4] = {};
#pragma unroll
        for (int dd = 0; dd < 32; ++dd) {
            float4 l4 = *(const float4*)&LsT[dd][ty * 4];
            float4 r4 = *(const float4*)&RsT[dd][tx * 4];
            float lv[4] = {l4.x, l4.y, l4.z, l4.w};
            float rv[4] = {r4.x, r4.y, r4.z, r4.w};
#pragma unroll
            for (int a_ = 0; a_ < 4; ++a_) {
#pragma unroll
                for (int b_ = 0; b_ < 4; ++b_) {
                    acc[a_][b_] = fmaf(lv[a_], rv[b_], acc[a_][b_]);
                }
            }
        }
#pragma unroll
        for (int a_ = 0; a_ < 4; ++a_) {
            float4 o;
            o.x = acc[a_][0] * SCALER; o.y = acc[a_][1] * SCALER;
            o.z = acc[a_][2] * SCALER; o.w = acc[a_][3] * SCALER;
            *(float4*)&Sp[(r0 + ty * 4 + a_) * N + c0 + tx * 4] = o;
        }
    }
}

// ---------------- K3: maxima ----------------
__global__ void maxX_kernel(const float* __restrict__ S, float* __restrict__ mX) {
    const int h = blockIdx.x;
    const float* Xp = S + h * (N * N);
    float m = -3.0e38f;
    for (int i = threadIdx.x; i < N * N; i += 256) m = fmaxf(m, Xp[i]);
    __shared__ float red[256];
    red[threadIdx.x] = m;
    __syncthreads();
    for (int s = 128; s > 0; s >>= 1) {
        if (threadIdx.x < s) red[threadIdx.x] = fmaxf(red[threadIdx.x], red[threadIdx.x + s]);
        __syncthreads();
    }
    if (threadIdx.x == 0) mX[h] = red[0];
}

__global__ void maxY_kernel(const float* __restrict__ S, float* __restrict__ mY) {
    const int h = blockIdx.x;
    const int i = threadIdx.x;  // 384 threads, one per column
    const float* Yp = S + (H * N * N) + h * (N * N);
    float m = -3.0e38f;
    for (int k = 0; k < N; ++k) m = fmaxf(m, Yp[k * N + i]);
    mY[h * N + i] = m;
}

__global__ void maxZ_kernel(const float* __restrict__ S, float* __restrict__ mZ) {
    const int h = blockIdx.y;
    const int i = blockIdx.x * 4 + (threadIdx.x >> 6);
    const int lane = threadIdx.x & 63;
    const float* Zrow = S + 2 * (H * N * N) + h * (N * N) + i * N;
    float m = -3.0e38f;
    for (int q = lane; q < N; q += 64) m = fmaxf(m, Zrow[q]);
#pragma unroll
    for (int off = 32; off; off >>= 1) m = fmaxf(m, __shfl_down(m, off));
    if (lane == 0) mZ[h * N + i] = m;
}

// ---------------- K4: exp (X,Z in place; Y -> transposed Yt) ----------------
__global__ void exp_kernel(float* __restrict__ S, const float* __restrict__ mX,
                           const float* __restrict__ mY, const float* __restrict__ mZ,
                           float* __restrict__ Yt) {
    int f4 = blockIdx.x * 256 + threadIdx.x;
    if (f4 >= 3 * H * N * N / 4) return;
    int flat = f4 * 4;
    int t = flat / (H * N * N);
    int rem = flat - t * (H * N * N);
    int h = rem / (N * N);
    int rc = rem - h * (N * N);
    int r = rc / N;
    int c = rc - r * N;
    float4 v = *(float4*)&S[flat];
    if (t == 0) {
        float m = mX[h];
        v.x = expf(v.x - m); v.y = expf(v.y - m); v.z = expf(v.z - m); v.w = expf(v.w - m);
        *(float4*)&S[flat] = v;
    } else if (t == 2) {
        float m = mZ[h * N + r];
        v.x = expf(v.x - m); v.y = expf(v.y - m); v.z = expf(v.z - m); v.w = expf(v.w - m);
        *(float4*)&S[flat] = v;
    } else {
        float* Yth = Yt + h * (N * N);
        Yth[(c + 0) * N + r] = expf(v.x - mY[h * N + c + 0]);
        Yth[(c + 1) * N + r] = expf(v.y - mY[h * N + c + 1]);
        Yth[(c + 2) * N + r] = expf(v.z - mY[h * N + c + 2]);
        Yth[(c + 3) * N + r] = expf(v.w - mY[h * N + c + 3]);
    }
}

// ---------------- K5: cubic contraction ----------------
// block = (dslot 0..32, i-tile 0..5, head). dslot<32: Num[:,dslot]; dslot==32: Den.
// M[i,k] = sum_j Z[i,j] * (X[j,k]*vj[j,d]);  out[i] = sum_k M[i,k]*Yt[i,k]*vk[k,d]
__global__ __launch_bounds__(256, 2) void cubic_kernel(const float* __restrict__ S,
                                                       const float* __restrict__ Yt,
                                                       const float* __restrict__ proj,
                                                       float* __restrict__ NumB,
                                                       float* __restrict__ DenB) {
    const int dslot = blockIdx.x;      // 0..32
    const int i0 = blockIdx.y * 64;
    const int h = blockIdx.z;
    const int tid = threadIdx.x;
    const int kg = tid & 31, ig = tid >> 5;
    __shared__ float Zt[32][68];       // [j][i]
    __shared__ float Xd[32][392];      // [j][k]
    __shared__ float vkd[N];
    __shared__ float red[64][33];
    const float* Xh = S + h * (N * N);                     // exp'd X [j][k]
    const float* Zh = S + 2 * (H * N * N) + h * (N * N);   // exp'd Z [i][j]
    const float* Yth = Yt + h * (N * N);                   // exp'd Y^T [i][k]
    const float* vjh = proj + 3 * (H * N * D) + h * (N * D);
    const float* vkh = proj + 4 * (H * N * D) + h * (N * D);
    const bool den = (dslot == 32);
    for (int k = tid; k < N; k += 256) vkd[k] = den ? 1.0f : vkh[k * D + dslot];

    float acc[8][12];
#pragma unroll
    for (int a = 0; a < 8; ++a) {
#pragma unroll
        for (int b = 0; b < 12; ++b) acc[a][b] = 0.0f;
    }
    const int zi = tid >> 2, zj8 = (tid & 3) * 8;
    const int xj = tid >> 3, xk4 = (tid & 7) * 4;

    for (int jt = 0; jt < 12; ++jt) {
        const int j0 = jt * 32;
        __syncthreads();
        {
            float4 z0 = *(const float4*)&Zh[(i0 + zi) * N + j0 + zj8];
            float4 z1 = *(const float4*)&Zh[(i0 + zi) * N + j0 + zj8 + 4];
            Zt[zj8 + 0][zi] = z0.x; Zt[zj8 + 1][zi] = z0.y; Zt[zj8 + 2][zi] = z0.z; Zt[zj8 + 3][zi] = z0.w;
            Zt[zj8 + 4][zi] = z1.x; Zt[zj8 + 5][zi] = z1.y; Zt[zj8 + 6][zi] = z1.z; Zt[zj8 + 7][zi] = z1.w;
            float vjv = den ? 1.0f : vjh[(j0 + xj) * D + dslot];
#pragma unroll
            for (int q = 0; q < 12; ++q) {
                float4 x = *(const float4*)&Xh[(j0 + xj) * N + xk4 + q * 32];
                x.x *= vjv; x.y *= vjv; x.z *= vjv; x.w *= vjv;
                *(float4*)&Xd[xj][xk4 + q * 32] = x;
            }
        }
        __syncthreads();
#pragma unroll 4
        for (int j = 0; j < 32; ++j) {
            float4 za = *(const float4*)&Zt[j][ig * 8];
            float4 zb = *(const float4*)&Zt[j][ig * 8 + 4];
            float4 x0 = *(const float4*)&Xd[j][kg * 12];
            float4 x1 = *(const float4*)&Xd[j][kg * 12 + 4];
            float4 x2 = *(const float4*)&Xd[j][kg * 12 + 8];
            float zv[8] = {za.x, za.y, za.z, za.w, zb.x, zb.y, zb.z, zb.w};
            float xv[12] = {x0.x, x0.y, x0.z, x0.w, x1.x, x1.y, x1.z, x1.w, x2.x, x2.y, x2.z, x2.w};
#pragma unroll
            for (int a = 0; a < 8; ++a) {
#pragma unroll
                for (int b = 0; b < 12; ++b) {
                    acc[a][b] = fmaf(zv[a], xv[b], acc[a][b]);
                }
            }
        }
    }

    // epilogue: weight by Yt[i,k]*vk[k,d], reduce over k
    float part[8];
#pragma unroll
    for (int il = 0; il < 8; ++il) {
        const int i = i0 + ig * 8 + il;
        float4 y0 = *(const float4*)&Yth[i * N + kg * 12];
        float4 y1 = *(const float4*)&Yth[i * N + kg * 12 + 4];
        float4 y2 = *(const float4*)&Yth[i * N + kg * 12 + 8];
        float yv[12] = {y0.x, y0.y, y0.z, y0.w, y1.x, y1.y, y1.z, y1.w, y2.x, y2.y, y2.z, y2.w};
        float s = 0.0f;
#pragma unroll
        for (int b = 0; b < 12; ++b) {
            s = fmaf(acc[il][b] * yv[b], vkd[kg * 12 + b], s);
        }
        part[il] = s;
    }
    __syncthreads();
#pragma unroll
    for (int il = 0; il < 8; ++il) red[ig * 8 + il][kg] = part[il];
    __syncthreads();
    if (tid < 64) {
        float s = 0.0f;
#pragma unroll
        for (int kk = 0; kk < 32; ++kk) s += red[tid][kk];
        if (!den) NumB[h * (N * D) + (i0 + tid) * D + dslot] = s;
        else      DenB[h * N + i0 + tid] = s;
    }
}

// ---------------- K6: normalize + fp32 output [n, h*D+d] ----------------
__global__ void out_kernel(const float* __restrict__ NumB, const float* __restrict__ DenB,
                           float* __restrict__ out) {
    int idx = blockIdx.x * 256 + threadIdx.x;  // 0..98303
    int n = idx >> 8;
    int ch = idx & 255;
    int hh = ch >> 5, d = ch & 31;
    float v = NumB[hh * (N * D) + n * D + d] / (DenB[hh * N + n] + EPS);
    out[idx] = v;
}

extern "C" void kernel_launch(void* const* d_in, const int* in_sizes, int n_in,
                              void* d_out, int out_size, void* d_ws, size_t ws_size,
                              hipStream_t stream) {
    const float* hs = (const float*)d_in[0];
    const float* W  = (const float*)d_in[1];
    float* ws = (float*)d_ws;
    float* proj = ws + PROJ_OFF;
    float* S    = ws + S_OFF;
    float* Yt   = ws + YT_OFF;
    float* mX   = ws + MX_OFF;
    float* mY   = ws + MY_OFF;
    float* mZ   = ws + MZ_OFF;
    float* NumB = ws + NUM_OFF;
    float* DenB = ws + DEN_OFF;
    float* out = (float*)d_out;

    proj_kernel<<<dim3(20, 6), 256, 0, stream>>>(hs, W, proj);
    scores_kernel<<<dim3(6, 8, 3), 256, 0, stream>>>(proj, S);
    maxX_kernel<<<8, 256, 0, stream>>>(S, mX);
    maxY_kernel<<<8, 384, 0, stream>>>(S, mY);
    maxZ_kernel<<<dim3(96, 8), 256, 0, stream>>>(S, mZ);
    exp_kernel<<<3456, 256, 0, stream>>>(S, mX, mY, mZ, Yt);
    cubic_kernel<<<dim3(33, 6, 8), 256, 0, stream>>>(S, Yt, proj, NumB, DenB);
    out_kernel<<<(H * N * D) / 256, 256, 0, stream>>>(NumB, DenB, out);
}

// Round 3
// 315.265 us; speedup vs baseline: 1.7888x; 1.7888x over previous
//
#include <hip/hip_runtime.h>
#include <hip/hip_bf16.h>

typedef unsigned short u16;
typedef __attribute__((ext_vector_type(8))) short short8;
typedef __attribute__((ext_vector_type(4))) float f32x4;

#define H 8
#define N 384
#define D 32
#define CIN 256
#define HNN (H * N * N)
#define SCALER 0.17677669529663687f
#define EPS 1e-9f

// workspace float offsets
#define PROJ_OFF 0u              // 5*H*N*D = 491520: a,b,c,vj,vk as [5][H][N][D]
#define S_OFF    491520u         // 3*H*N*N: t=0 XT[k][j], t=1 YT[i][k], t=2 Z[i][j]
#define VJT_OFF  4030464u        // H*D*N = 98304: vj transposed [h][d][n]
#define VKT_OFF  4128768u        // H*D*N
#define MX_OFF   4227072u        // 8
#define MY_OFF   4227080u        // H*N
#define MZ_OFF   4230152u        // H*N
#define NUM_OFF  4233224u        // H*N*D
#define DEN_OFF  4331528u        // H*N
#define XBF_OFF  4334600u        // ushort[H*N*N] = 589824 float slots (XT bf16)
#define ZBF_OFF  4924424u        // ushort[H*N*N] (Z bf16)

__device__ inline float bf2f(u16 u) {
    union { unsigned int x; float f; } c; c.x = ((unsigned int)u) << 16; return c.f;
}
__device__ inline u16 f2bf(float f) {
    unsigned int x = __float_as_uint(f);
    return (u16)((x + 0x7FFFu + ((x >> 16) & 1u)) >> 16);
}

// ---------------- K1: projection GEMM  wx[n,m] = sum_k hs[n,k]*W[m,k] ----------------
__global__ __launch_bounds__(256) void proj_kernel(const float* __restrict__ hs,
                                                   const float* __restrict__ W,
                                                   float* __restrict__ proj,
                                                   float* __restrict__ projT) {
    __shared__ float hs_s[64][68];
    __shared__ float w_s[64][68];
    const int tid = threadIdx.x;
    const int tx = tid & 15, ty = tid >> 4;
    const int m0 = blockIdx.x * 64, n0 = blockIdx.y * 64;
    float acc[4][4] = {};
    for (int k0 = 0; k0 < CIN; k0 += 64) {
        __syncthreads();
#pragma unroll
        for (int rep = 0; rep < 4; ++rep) {
            int lin = rep * 1024 + tid * 4;
            int rl = lin >> 6, kl = lin & 63;
            float4 hv = *(const float4*)&hs[(n0 + rl) * CIN + k0 + kl];
            hs_s[kl + 0][rl] = hv.x; hs_s[kl + 1][rl] = hv.y;
            hs_s[kl + 2][rl] = hv.z; hs_s[kl + 3][rl] = hv.w;
            float4 wv = *(const float4*)&W[(m0 + rl) * CIN + k0 + kl];
            w_s[kl + 0][rl] = wv.x; w_s[kl + 1][rl] = wv.y;
            w_s[kl + 2][rl] = wv.z; w_s[kl + 3][rl] = wv.w;
        }
        __syncthreads();
#pragma unroll 16
        for (int kk = 0; kk < 64; ++kk) {
            float4 a4 = *(const float4*)&hs_s[kk][ty * 4];
            float4 b4 = *(const float4*)&w_s[kk][tx * 4];
            float av[4] = {a4.x, a4.y, a4.z, a4.w};
            float bv[4] = {b4.x, b4.y, b4.z, b4.w};
#pragma unroll
            for (int a_ = 0; a_ < 4; ++a_) {
#pragma unroll
                for (int b_ = 0; b_ < 4; ++b_) {
                    acc[a_][b_] = fmaf(av[a_], bv[b_], acc[a_][b_]);
                }
            }
        }
    }
#pragma unroll
    for (int a_ = 0; a_ < 4; ++a_) {
        int n = n0 + ty * 4 + a_;
#pragma unroll
        for (int b_ = 0; b_ < 4; ++b_) {
            int m = m0 + tx * 4 + b_;
            int s = m >> 8, hh = (m >> 5) & 7, d = m & 31;
            proj[s * (H * N * D) + hh * (N * D) + n * D + d] = acc[a_][b_];
            if (s >= 3) projT[(s - 3) * (H * D * N) + hh * (D * N) + d * N + n] = acc[a_][b_];
        }
    }
}

// ---------------- K2: scores ----------------
// t=0: XT[k,j] = c_k . b_j ; t=1: YT[i,k] = a_i . c_k ; t=2: Z[i,j] = a_i . b_j
__global__ __launch_bounds__(256) void scores_kernel(const float* __restrict__ proj,
                                                     float* __restrict__ S) {
    __shared__ float LsT[32][68];
    __shared__ float RsT[32][68];
    const int tid = threadIdx.x, tx = tid & 15, ty = tid >> 4;
    const int r0 = blockIdx.x * 64;
    const int h = blockIdx.y;
    const int t = blockIdx.z;
    const int Lidx = (t == 0) ? 2 : 0;
    const int Ridx = (t == 1) ? 2 : 1;
    const float* Lp = proj + Lidx * (H * N * D) + h * (N * D);
    const float* Rp = proj + Ridx * (H * N * D) + h * (N * D);
    float* Sp = S + t * HNN + h * (N * N);
    {
        int i = tid >> 2, d8 = (tid & 3) * 8;
        float4 v0 = *(const float4*)&Lp[(r0 + i) * D + d8];
        float4 v1 = *(const float4*)&Lp[(r0 + i) * D + d8 + 4];
        LsT[d8 + 0][i] = v0.x; LsT[d8 + 1][i] = v0.y; LsT[d8 + 2][i] = v0.z; LsT[d8 + 3][i] = v0.w;
        LsT[d8 + 4][i] = v1.x; LsT[d8 + 5][i] = v1.y; LsT[d8 + 6][i] = v1.z; LsT[d8 + 7][i] = v1.w;
    }
    for (int c0 = 0; c0 < N; c0 += 64) {
        __syncthreads();
        {
            int i = tid >> 2, d8 = (tid & 3) * 8;
            float4 v0 = *(const float4*)&Rp[(c0 + i) * D + d8];
            float4 v1 = *(const float4*)&Rp[(c0 + i) * D + d8 + 4];
            RsT[d8 + 0][i] = v0.x; RsT[d8 + 1][i] = v0.y; RsT[d8 + 2][i] = v0.z; RsT[d8 + 3][i] = v0.w;
            RsT[d8 + 4][i] = v1.x; RsT[d8 + 5][i] = v1.y; RsT[d8 + 6][i] = v1.z; RsT[d8 + 7][i] = v1.w;
        }
        __syncthreads();
        float acc[4][4] = {};
#pragma unroll
        for (int dd = 0; dd < 32; ++dd) {
            float4 l4 = *(const float4*)&LsT[dd][ty * 4];
            float4 r4 = *(const float4*)&RsT[dd][tx * 4];
            float lv[4] = {l4.x, l4.y, l4.z, l4.w};
            float rv[4] = {r4.x, r4.y, r4.z, r4.w};
#pragma unroll
            for (int a_ = 0; a_ < 4; ++a_) {
#pragma unroll
                for (int b_ = 0; b_ < 4; ++b_) {
                    acc[a_][b_] = fmaf(lv[a_], rv[b_], acc[a_][b_]);
                }
            }
        }
#pragma unroll
        for (int a_ = 0; a_ < 4; ++a_) {
            float4 o;
            o.x = acc[a_][0] * SCALER; o.y = acc[a_][1] * SCALER;
            o.z = acc[a_][2] * SCALER; o.w = acc[a_][3] * SCALER;
            *(float4*)&Sp[(r0 + ty * 4 + a_) * N + c0 + tx * 4] = o;
        }
    }
}

// ---------------- K3: maxima ----------------
__global__ void maxX_kernel(const float* __restrict__ S, float* __restrict__ mX) {
    const int h = blockIdx.x;
    const float* Xp = S + h * (N * N);
    float m = -3.0e38f;
    for (int i = threadIdx.x; i < N * N; i += 256) m = fmaxf(m, Xp[i]);
    __shared__ float red[256];
    red[threadIdx.x] = m;
    __syncthreads();
    for (int s = 128; s > 0; s >>= 1) {
        if (threadIdx.x < s) red[threadIdx.x] = fmaxf(red[threadIdx.x], red[threadIdx.x + s]);
        __syncthreads();
    }
    if (threadIdx.x == 0) mX[h] = red[0];
}

__global__ void rowmax_kernel(const float* __restrict__ base, float* __restrict__ mrow) {
    const int h = blockIdx.y;
    const int r = blockIdx.x * 4 + (threadIdx.x >> 6);
    const int lane = threadIdx.x & 63;
    const float* row = base + h * (N * N) + r * N;
    float m = -3.0e38f;
    for (int q = lane; q < N; q += 64) m = fmaxf(m, row[q]);
#pragma unroll
    for (int off = 32; off; off >>= 1) m = fmaxf(m, __shfl_down(m, off));
    if (lane == 0) mrow[h * N + r] = m;
}

// ---------------- K4: exp.  t=1 writes f32 in place; t=0/2 write bf16 copies ----------------
__global__ void exp_kernel(float* __restrict__ S, const float* __restrict__ mX,
                           const float* __restrict__ mY, const float* __restrict__ mZ,
                           u16* __restrict__ Xbf, u16* __restrict__ Zbf) {
    int f8 = blockIdx.x * 256 + threadIdx.x;  // 442368 total
    int flat = f8 * 8;
    int t = flat / HNN;
    int rem = flat - t * HNN;
    int h = rem / (N * N);
    int rc = rem - h * (N * N);
    int r = rc / N;
    float m = (t == 0) ? mX[h] : ((t == 1) ? mY[h * N + r] : mZ[h * N + r]);
    float4 v0 = *(float4*)&S[flat];
    float4 v1 = *(float4*)&S[flat + 4];
    float e[8] = {expf(v0.x - m), expf(v0.y - m), expf(v0.z - m), expf(v0.w - m),
                  expf(v1.x - m), expf(v1.y - m), expf(v1.z - m), expf(v1.w - m)};
    if (t == 1) {
        float4 o0 = {e[0], e[1], e[2], e[3]}, o1 = {e[4], e[5], e[6], e[7]};
        *(float4*)&S[flat] = o0;
        *(float4*)&S[flat + 4] = o1;
    } else {
        short8 ov;
#pragma unroll
        for (int q = 0; q < 8; ++q) ov[q] = (short)f2bf(e[q]);
        u16* dst = (t == 0 ? Xbf : Zbf) + h * (N * N) + rc;
        *(short8*)dst = ov;
    }
}

// ---------------- K5: cubic contraction via MFMA bf16 ----------------
// block (d 0..32, i-tile 0..5, h). d<32: Num[:,d]; d==32: Den.
// M[i,k] = sum_j (Z[i,j]*vj[j,d])_bf16 * XT[k,j]_bf16 ; numAcc[i] += sum_k M*YT[i,k]*vk[k,d]
__global__ __launch_bounds__(256, 2) void cubic_mfma(
        const u16* __restrict__ Xbf, const u16* __restrict__ Zbf,
        const float* __restrict__ Yt, const float* __restrict__ vjT,
        const float* __restrict__ vkT, float* __restrict__ NumB,
        float* __restrict__ DenB) {
    const int d  = blockIdx.x;        // 0..32 (32 = Den)
    const int i0 = blockIdx.y * 64;
    const int h  = blockIdx.z;
    const int tid = threadIdx.x;
    const int w = tid >> 6, lane = tid & 63;
    const bool den = (d == 32);
    __shared__ u16 A_lds[64 * N];     // [i][j] swizzled: j ^= (i&7)<<3
    __shared__ u16 B_lds[32 * N];     // [kk][j] swizzled: j ^= (kk&7)<<3
    const u16* Zh = Zbf + h * (N * N);
    const u16* Xh = Xbf + h * (N * N);
    const float* Yth = Yt + h * (N * N);
    const float* vjd = vjT + h * (D * N) + (den ? 0 : d) * N;
    const float* vkd = vkT + h * (D * N) + (den ? 0 : d) * N;

    // ---- A-prep (once per block)
    for (int it = 0; it < 12; ++it) {
        int c = it * 256 + tid;       // 3072 chunks of 8 elems
        int ii = c / 48;
        int jb = (c - ii * 48) * 8;
        const short8 zv = *(const short8*)&Zh[(i0 + ii) * N + jb];
        short8 ov;
#pragma unroll
        for (int e = 0; e < 8; ++e) {
            float f = bf2f((u16)zv[e]);
            if (!den) f *= vjd[jb + e];
            ov[e] = (short)f2bf(f);
        }
        *(short8*)&A_lds[ii * N + (jb ^ ((ii & 7) << 3))] = ov;
    }

    float numAcc[4] = {0.f, 0.f, 0.f, 0.f};
    const int arow = w * 16 + (lane & 15);
    const int aj0 = (lane >> 4) * 8;
    const int bk = lane & 15;
    const int erow = i0 + w * 16 + ((lane >> 4) << 2);
    const int ek = lane & 15;

    for (int kt = 0; kt < 12; ++kt) {
        const int k0 = kt * 32;
        __syncthreads();  // B_lds free from previous iteration
        for (int it = 0; it < 6; ++it) {
            int c = it * 256 + tid;   // 1536 chunks
            int kk = c / 48;
            int jb = (c - kk * 48) * 8;
            const short8 xv = *(const short8*)&Xh[(k0 + kk) * N + jb];
            *(short8*)&B_lds[kk * N + (jb ^ ((kk & 7) << 3))] = xv;
        }
        __syncthreads();
        f32x4 acc0 = {0.f, 0.f, 0.f, 0.f}, acc1 = {0.f, 0.f, 0.f, 0.f};
#pragma unroll
        for (int js = 0; js < 12; ++js) {
            int j = js * 32 + aj0;
            const short8 av  = *(const short8*)&A_lds[arow * N + (j ^ ((arow & 7) << 3))];
            const short8 bv0 = *(const short8*)&B_lds[bk * N + (j ^ ((bk & 7) << 3))];
            const short8 bv1 = *(const short8*)&B_lds[(bk + 16) * N + (j ^ (((bk + 16) & 7) << 3))];
            acc0 = __builtin_amdgcn_mfma_f32_16x16x32_bf16(av, bv0, acc0, 0, 0, 0);
            acc1 = __builtin_amdgcn_mfma_f32_16x16x32_bf16(av, bv1, acc1, 0, 0, 0);
        }
#pragma unroll
        for (int reg = 0; reg < 4; ++reg) {
            const int irow = erow + reg;
            float w0 = Yth[irow * N + k0 + ek];
            float w1 = Yth[irow * N + k0 + 16 + ek];
            if (!den) { w0 *= vkd[k0 + ek]; w1 *= vkd[k0 + 16 + ek]; }
            numAcc[reg] += acc0[reg] * w0 + acc1[reg] * w1;
        }
    }
#pragma unroll
    for (int reg = 0; reg < 4; ++reg) {
        float v = numAcc[reg];
        v += __shfl_xor(v, 1); v += __shfl_xor(v, 2);
        v += __shfl_xor(v, 4); v += __shfl_xor(v, 8);
        numAcc[reg] = v;
    }
    if ((lane & 15) == 0) {
#pragma unroll
        for (int reg = 0; reg < 4; ++reg) {
            const int irow = erow + reg;
            if (!den) NumB[h * (N * D) + irow * D + d] = numAcc[reg];
            else      DenB[h * N + irow] = numAcc[reg];
        }
    }
}

// ---------------- K6: normalize + fp32 output [n, h*D+d] ----------------
__global__ void out_kernel(const float* __restrict__ NumB, const float* __restrict__ DenB,
                           float* __restrict__ out) {
    int idx = blockIdx.x * 256 + threadIdx.x;  // 0..98303
    int n = idx >> 8;
    int ch = idx & 255;
    int hh = ch >> 5, d = ch & 31;
    float v = NumB[hh * (N * D) + n * D + d] / (DenB[hh * N + n] + EPS);
    out[idx] = v;
}

extern "C" void kernel_launch(void* const* d_in, const int* in_sizes, int n_in,
                              void* d_out, int out_size, void* d_ws, size_t ws_size,
                              hipStream_t stream) {
    const float* hs = (const float*)d_in[0];
    const float* W  = (const float*)d_in[1];
    float* ws = (float*)d_ws;
    float* proj  = ws + PROJ_OFF;
    float* S     = ws + S_OFF;
    float* projT = ws + VJT_OFF;    // vj rows, then vk rows at +H*D*N
    float* mX    = ws + MX_OFF;
    float* mY    = ws + MY_OFF;
    float* mZ    = ws + MZ_OFF;
    float* NumB  = ws + NUM_OFF;
    float* DenB  = ws + DEN_OFF;
    u16*   Xbf   = (u16*)(ws + XBF_OFF);
    u16*   Zbf   = (u16*)(ws + ZBF_OFF);
    float* out = (float*)d_out;

    proj_kernel<<<dim3(20, 6), 256, 0, stream>>>(hs, W, proj, projT);
    scores_kernel<<<dim3(6, 8, 3), 256, 0, stream>>>(proj, S);
    maxX_kernel<<<8, 256, 0, stream>>>(S, mX);
    rowmax_kernel<<<dim3(96, 8), 256, 0, stream>>>(S + HNN, mY);
    rowmax_kernel<<<dim3(96, 8), 256, 0, stream>>>(S + 2 * HNN, mZ);
    exp_kernel<<<1728, 256, 0, stream>>>(S, mX, mY, mZ, Xbf, Zbf);
    cubic_mfma<<<dim3(33, 6, 8), 256, 0, stream>>>(Xbf, Zbf, S + HNN, ws + VJT_OFF,
                                                   ws + VKT_OFF, NumB, DenB);
    out_kernel<<<(H * N * D) / 256, 256, 0, stream>>>(NumB, DenB, out);
}

// Round 4
// 291.917 us; speedup vs baseline: 1.9318x; 1.0800x over previous
//
#include <hip/hip_runtime.h>
#include <hip/hip_bf16.h>

typedef unsigned short u16;
typedef __attribute__((ext_vector_type(8))) short short8;
typedef __attribute__((ext_vector_type(4))) float f32x4;

#define H 8
#define N 384
#define D 32
#define CIN 256
#define HNN (H * N * N)
#define SCALER 0.17677669529663687f
#define EPS 1e-9f

// workspace float offsets
#define PROJ_OFF 0u              // 5*H*N*D = 491520: a,b,c,vj,vk as [5][H][N][D]
#define S_OFF    491520u         // 3*H*N*N: t=0 XT[k][j], t=1 YT[i][k], t=2 Z[i][j]
#define VJT_OFF  4030464u        // H*D*N = 98304: vj transposed [h][d][n]
#define VKT_OFF  4128768u        // H*D*N
#define MX_OFF   4227072u        // 8
#define MY_OFF   4227080u        // H*N
#define MZ_OFF   4230152u        // H*N
#define NUM_OFF  4233224u        // H*N*D
#define DEN_OFF  4331528u        // H*N
#define XBF_OFF  4334600u        // ushort[H*N*N] = 589824 float slots (XT bf16)
#define ZBF_OFF  4924424u        // ushort[H*N*N] (Z bf16)

__device__ inline float bf2f(u16 u) {
    union { unsigned int x; float f; } c; c.x = ((unsigned int)u) << 16; return c.f;
}
__device__ inline u16 f2bf(float f) {
    unsigned int x = __float_as_uint(f);
    return (u16)((x + 0x7FFFu + ((x >> 16) & 1u)) >> 16);
}

// ---------------- K1: projection GEMM  wx[n,m] = sum_k hs[n,k]*W[m,k] ----------------
__global__ __launch_bounds__(256) void proj_kernel(const float* __restrict__ hs,
                                                   const float* __restrict__ W,
                                                   float* __restrict__ proj,
                                                   float* __restrict__ projT) {
    __shared__ float hs_s[64][68];
    __shared__ float w_s[64][68];
    const int tid = threadIdx.x;
    const int tx = tid & 15, ty = tid >> 4;
    const int m0 = blockIdx.x * 64, n0 = blockIdx.y * 64;
    float acc[4][4] = {};
    for (int k0 = 0; k0 < CIN; k0 += 64) {
        __syncthreads();
#pragma unroll
        for (int rep = 0; rep < 4; ++rep) {
            int lin = rep * 1024 + tid * 4;
            int rl = lin >> 6, kl = lin & 63;
            float4 hv = *(const float4*)&hs[(n0 + rl) * CIN + k0 + kl];
            hs_s[kl + 0][rl] = hv.x; hs_s[kl + 1][rl] = hv.y;
            hs_s[kl + 2][rl] = hv.z; hs_s[kl + 3][rl] = hv.w;
            float4 wv = *(const float4*)&W[(m0 + rl) * CIN + k0 + kl];
            w_s[kl + 0][rl] = wv.x; w_s[kl + 1][rl] = wv.y;
            w_s[kl + 2][rl] = wv.z; w_s[kl + 3][rl] = wv.w;
        }
        __syncthreads();
#pragma unroll 16
        for (int kk = 0; kk < 64; ++kk) {
            float4 a4 = *(const float4*)&hs_s[kk][ty * 4];
            float4 b4 = *(const float4*)&w_s[kk][tx * 4];
            float av[4] = {a4.x, a4.y, a4.z, a4.w};
            float bv[4] = {b4.x, b4.y, b4.z, b4.w};
#pragma unroll
            for (int a_ = 0; a_ < 4; ++a_) {
#pragma unroll
                for (int b_ = 0; b_ < 4; ++b_) {
                    acc[a_][b_] = fmaf(av[a_], bv[b_], acc[a_][b_]);
                }
            }
        }
    }
#pragma unroll
    for (int a_ = 0; a_ < 4; ++a_) {
        int n = n0 + ty * 4 + a_;
#pragma unroll
        for (int b_ = 0; b_ < 4; ++b_) {
            int m = m0 + tx * 4 + b_;
            int s = m >> 8, hh = (m >> 5) & 7, d = m & 31;
            proj[s * (H * N * D) + hh * (N * D) + n * D + d] = acc[a_][b_];
            if (s >= 3) projT[(s - 3) * (H * D * N) + hh * (D * N) + d * N + n] = acc[a_][b_];
        }
    }
}

// ---------------- K2: scores ----------------
// t=0: XT[k,j] = c_k . b_j ; t=1: YT[i,k] = a_i . c_k ; t=2: Z[i,j] = a_i . b_j
__global__ __launch_bounds__(256) void scores_kernel(const float* __restrict__ proj,
                                                     float* __restrict__ S) {
    __shared__ float LsT[32][68];
    __shared__ float RsT[32][68];
    const int tid = threadIdx.x, tx = tid & 15, ty = tid >> 4;
    const int r0 = blockIdx.x * 64;
    const int h = blockIdx.y;
    const int t = blockIdx.z;
    const int Lidx = (t == 0) ? 2 : 0;
    const int Ridx = (t == 1) ? 2 : 1;
    const float* Lp = proj + Lidx * (H * N * D) + h * (N * D);
    const float* Rp = proj + Ridx * (H * N * D) + h * (N * D);
    float* Sp = S + t * HNN + h * (N * N);
    {
        int i = tid >> 2, d8 = (tid & 3) * 8;
        float4 v0 = *(const float4*)&Lp[(r0 + i) * D + d8];
        float4 v1 = *(const float4*)&Lp[(r0 + i) * D + d8 + 4];
        LsT[d8 + 0][i] = v0.x; LsT[d8 + 1][i] = v0.y; LsT[d8 + 2][i] = v0.z; LsT[d8 + 3][i] = v0.w;
        LsT[d8 + 4][i] = v1.x; LsT[d8 + 5][i] = v1.y; LsT[d8 + 6][i] = v1.z; LsT[d8 + 7][i] = v1.w;
    }
    for (int c0 = 0; c0 < N; c0 += 64) {
        __syncthreads();
        {
            int i = tid >> 2, d8 = (tid & 3) * 8;
            float4 v0 = *(const float4*)&Rp[(c0 + i) * D + d8];
            float4 v1 = *(const float4*)&Rp[(c0 + i) * D + d8 + 4];
            RsT[d8 + 0][i] = v0.x; RsT[d8 + 1][i] = v0.y; RsT[d8 + 2][i] = v0.z; RsT[d8 + 3][i] = v0.w;
            RsT[d8 + 4][i] = v1.x; RsT[d8 + 5][i] = v1.y; RsT[d8 + 6][i] = v1.z; RsT[d8 + 7][i] = v1.w;
        }
        __syncthreads();
        float acc[4][4] = {};
#pragma unroll
        for (int dd = 0; dd < 32; ++dd) {
            float4 l4 = *(const float4*)&LsT[dd][ty * 4];
            float4 r4 = *(const float4*)&RsT[dd][tx * 4];
            float lv[4] = {l4.x, l4.y, l4.z, l4.w};
            float rv[4] = {r4.x, r4.y, r4.z, r4.w};
#pragma unroll
            for (int a_ = 0; a_ < 4; ++a_) {
#pragma unroll
                for (int b_ = 0; b_ < 4; ++b_) {
                    acc[a_][b_] = fmaf(lv[a_], rv[b_], acc[a_][b_]);
                }
            }
        }
#pragma unroll
        for (int a_ = 0; a_ < 4; ++a_) {
            float4 o;
            o.x = acc[a_][0] * SCALER; o.y = acc[a_][1] * SCALER;
            o.z = acc[a_][2] * SCALER; o.w = acc[a_][3] * SCALER;
            *(float4*)&Sp[(r0 + ty * 4 + a_) * N + c0 + tx * 4] = o;
        }
    }
}

// ---------------- K3: maxima ----------------
__global__ void maxX_kernel(const float* __restrict__ S, float* __restrict__ mX) {
    const int h = blockIdx.x;
    const float* Xp = S + h * (N * N);
    float m = -3.0e38f;
    for (int i = threadIdx.x; i < N * N; i += 256) m = fmaxf(m, Xp[i]);
    __shared__ float red[256];
    red[threadIdx.x] = m;
    __syncthreads();
    for (int s = 128; s > 0; s >>= 1) {
        if (threadIdx.x < s) red[threadIdx.x] = fmaxf(red[threadIdx.x], red[threadIdx.x + s]);
        __syncthreads();
    }
    if (threadIdx.x == 0) mX[h] = red[0];
}

// fused row-max for YT (z=0 -> mY) and Z (z=1 -> mZ)
__global__ void rowmax_kernel(const float* __restrict__ S, float* __restrict__ mY,
                              float* __restrict__ mZ) {
    const int z = blockIdx.z;
    const int h = blockIdx.y;
    const int r = blockIdx.x * 4 + (threadIdx.x >> 6);
    const int lane = threadIdx.x & 63;
    const float* row = S + (1 + z) * HNN + h * (N * N) + r * N;
    float m = -3.0e38f;
    for (int q = lane; q < N; q += 64) m = fmaxf(m, row[q]);
#pragma unroll
    for (int off = 32; off; off >>= 1) m = fmaxf(m, __shfl_down(m, off));
    if (lane == 0) (z == 0 ? mY : mZ)[h * N + r] = m;
}

// ---------------- K4: exp.  t=1 writes f32 in place; t=0/2 write bf16 copies ----------------
__global__ void exp_kernel(float* __restrict__ S, const float* __restrict__ mX,
                           const float* __restrict__ mY, const float* __restrict__ mZ,
                           u16* __restrict__ Xbf, u16* __restrict__ Zbf) {
    int f8 = blockIdx.x * 256 + threadIdx.x;  // 442368 total
    int flat = f8 * 8;
    int t = flat / HNN;
    int rem = flat - t * HNN;
    int h = rem / (N * N);
    int rc = rem - h * (N * N);
    int r = rc / N;
    float m = (t == 0) ? mX[h] : ((t == 1) ? mY[h * N + r] : mZ[h * N + r]);
    float4 v0 = *(float4*)&S[flat];
    float4 v1 = *(float4*)&S[flat + 4];
    float e[8] = {expf(v0.x - m), expf(v0.y - m), expf(v0.z - m), expf(v0.w - m),
                  expf(v1.x - m), expf(v1.y - m), expf(v1.z - m), expf(v1.w - m)};
    if (t == 1) {
        float4 o0 = {e[0], e[1], e[2], e[3]}, o1 = {e[4], e[5], e[6], e[7]};
        *(float4*)&S[flat] = o0;
        *(float4*)&S[flat + 4] = o1;
    } else {
        short8 ov;
#pragma unroll
        for (int q = 0; q < 8; ++q) ov[q] = (short)f2bf(e[q]);
        u16* dst = (t == 0 ? Xbf : Zbf) + h * (N * N) + rc;
        *(short8*)dst = ov;
    }
}

// ---------------- K5: cubic contraction via MFMA bf16, v3 ----------------
// block (d 0..32, i-tile of 64, h). A = (Z .* vj_d) bf16 in LDS (once).
// B = XT bf16 straight from global to registers (L2-resident).
// Wave w owns k in [w*96, w*96+96): acc[fi 0..3][fk 0..5] = M[64i x 96k].
// Epilogue (once): Num_i += sum_k M[i,k]*YT[i,k]*vk[k,d]; cross-wave LDS reduce.
__global__ __launch_bounds__(256, 3) void cubic_mfma(
        const u16* __restrict__ Xbf, const u16* __restrict__ Zbf,
        const float* __restrict__ Yt, const float* __restrict__ vjT,
        const float* __restrict__ vkT, float* __restrict__ NumB,
        float* __restrict__ DenB) {
    const int d  = blockIdx.x;        // 0..32 (32 = Den)
    const int i0 = blockIdx.y * 64;
    const int h  = blockIdx.z;
    const int tid = threadIdx.x;
    const int w = tid >> 6, lane = tid & 63;
    const bool den = (d == 32);
    __shared__ u16 A_lds[64 * N];     // [i][j], chunk-swizzled: jchunk ^= (i&7)
    __shared__ float red[4][64];
    const u16* Zh = Zbf + h * (N * N);
    const u16* Xh = Xbf + h * (N * N);
    const float* Yth = Yt + h * (N * N);
    const float* vjd = vjT + h * (D * N) + (den ? 0 : d) * N;
    const float* vkd = vkT + h * (D * N) + (den ? 0 : d) * N;

    // ---- A-prep: 64 rows x 48 chunks(short8); thread -> (row = tid>>2, 12 chunks)
    {
        const int row = tid >> 2;
        const int cb = (tid & 3) * 12;
        const u16* zrow = &Zh[(i0 + row) * N];
        u16* arow = &A_lds[row * N];
        const int sw = (row & 7) << 3;
#pragma unroll
        for (int q = 0; q < 12; ++q) {
            const int jb = (cb + q) * 8;
            short8 zv = *(const short8*)&zrow[jb];
            short8 ov;
            if (den) {
                ov = zv;
            } else {
                float4 vj0 = *(const float4*)&vjd[jb];
                float4 vj1 = *(const float4*)&vjd[jb + 4];
                float vjv[8] = {vj0.x, vj0.y, vj0.z, vj0.w, vj1.x, vj1.y, vj1.z, vj1.w};
#pragma unroll
                for (int e = 0; e < 8; ++e) ov[e] = (short)f2bf(bf2f((u16)zv[e]) * vjv[e]);
            }
            *(short8*)&arow[jb ^ sw] = ov;
        }
    }
    __syncthreads();

    // ---- MFMA main loop: no barriers, k held in accumulators
    f32x4 acc[4][6];
#pragma unroll
    for (int fi = 0; fi < 4; ++fi)
#pragma unroll
        for (int fk = 0; fk < 6; ++fk) acc[fi][fk] = (f32x4){0.f, 0.f, 0.f, 0.f};

    const int l15 = lane & 15;
    const int jc = (lane >> 4) * 8;
    const int sw = (l15 & 7) << 3;    // fi*16 keeps row&7 == lane&7
    const int kwb = w * 96 + l15;

#pragma unroll 2
    for (int js = 0; js < 12; ++js) {
        const int j = js * 32 + jc;
        short8 a[4];
#pragma unroll
        for (int fi = 0; fi < 4; ++fi) {
            a[fi] = *(const short8*)&A_lds[(fi * 16 + l15) * N + (j ^ sw)];
        }
#pragma unroll
        for (int fk = 0; fk < 6; ++fk) {
            const short8 b = *(const short8*)&Xh[(kwb + fk * 16) * N + j];
            acc[0][fk] = __builtin_amdgcn_mfma_f32_16x16x32_bf16(a[0], b, acc[0][fk], 0, 0, 0);
            acc[1][fk] = __builtin_amdgcn_mfma_f32_16x16x32_bf16(a[1], b, acc[1][fk], 0, 0, 0);
            acc[2][fk] = __builtin_amdgcn_mfma_f32_16x16x32_bf16(a[2], b, acc[2][fk], 0, 0, 0);
            acc[3][fk] = __builtin_amdgcn_mfma_f32_16x16x32_bf16(a[3], b, acc[3][fk], 0, 0, 0);
        }
    }

    // ---- epilogue: weight by YT[i,k]*vk[k,d], reduce over k
    float np[4][4];
#pragma unroll
    for (int fi = 0; fi < 4; ++fi)
#pragma unroll
        for (int reg = 0; reg < 4; ++reg) np[fi][reg] = 0.f;

    const int rbase = (lane >> 4) << 2;
#pragma unroll
    for (int fk = 0; fk < 6; ++fk) {
        const int kcol = kwb + fk * 16;
        const float vkv = den ? 1.0f : vkd[kcol];
#pragma unroll
        for (int fi = 0; fi < 4; ++fi) {
#pragma unroll
            for (int reg = 0; reg < 4; ++reg) {
                const int irow = i0 + fi * 16 + rbase + reg;
                const float wgt = Yth[irow * N + kcol] * vkv;
                np[fi][reg] = fmaf(acc[fi][fk][reg], wgt, np[fi][reg]);
            }
        }
    }
#pragma unroll
    for (int fi = 0; fi < 4; ++fi) {
#pragma unroll
        for (int reg = 0; reg < 4; ++reg) {
            float v = np[fi][reg];
            v += __shfl_xor(v, 1); v += __shfl_xor(v, 2);
            v += __shfl_xor(v, 4); v += __shfl_xor(v, 8);
            np[fi][reg] = v;
        }
    }
    if (l15 == 0) {
#pragma unroll
        for (int fi = 0; fi < 4; ++fi)
#pragma unroll
            for (int reg = 0; reg < 4; ++reg)
                red[w][fi * 16 + rbase + reg] = np[fi][reg];
    }
    __syncthreads();
    if (tid < 64) {
        const float s = red[0][tid] + red[1][tid] + red[2][tid] + red[3][tid];
        if (!den) NumB[h * (N * D) + (i0 + tid) * D + d] = s;
        else      DenB[h * N + i0 + tid] = s;
    }
}

// ---------------- K6: normalize + fp32 output [n, h*D+d] ----------------
__global__ void out_kernel(const float* __restrict__ NumB, const float* __restrict__ DenB,
                           float* __restrict__ out) {
    int idx = blockIdx.x * 256 + threadIdx.x;  // 0..98303
    int n = idx >> 8;
    int ch = idx & 255;
    int hh = ch >> 5, d = ch & 31;
    float v = NumB[hh * (N * D) + n * D + d] / (DenB[hh * N + n] + EPS);
    out[idx] = v;
}

extern "C" void kernel_launch(void* const* d_in, const int* in_sizes, int n_in,
                              void* d_out, int out_size, void* d_ws, size_t ws_size,
                              hipStream_t stream) {
    const float* hs = (const float*)d_in[0];
    const float* W  = (const float*)d_in[1];
    float* ws = (float*)d_ws;
    float* proj  = ws + PROJ_OFF;
    float* S     = ws + S_OFF;
    float* projT = ws + VJT_OFF;    // vj rows, then vk rows at +H*D*N
    float* mX    = ws + MX_OFF;
    float* mY    = ws + MY_OFF;
    float* mZ    = ws + MZ_OFF;
    float* NumB  = ws + NUM_OFF;
    float* DenB  = ws + DEN_OFF;
    u16*   Xbf   = (u16*)(ws + XBF_OFF);
    u16*   Zbf   = (u16*)(ws + ZBF_OFF);
    float* out = (float*)d_out;

    proj_kernel<<<dim3(20, 6), 256, 0, stream>>>(hs, W, proj, projT);
    scores_kernel<<<dim3(6, 8, 3), 256, 0, stream>>>(proj, S);
    maxX_kernel<<<8, 256, 0, stream>>>(S, mX);
    rowmax_kernel<<<dim3(96, 8, 2), 256, 0, stream>>>(S, mY, mZ);
    exp_kernel<<<1728, 256, 0, stream>>>(S, mX, mY, mZ, Xbf, Zbf);
    cubic_mfma<<<dim3(33, 6, 8), 256, 0, stream>>>(Xbf, Zbf, S + HNN, ws + VJT_OFF,
                                                   ws + VKT_OFF, NumB, DenB);
    out_kernel<<<(H * N * D) / 256, 256, 0, stream>>>(NumB, DenB, out);
}

// Round 5
// 236.771 us; speedup vs baseline: 2.3818x; 1.2329x over previous
//
#include <hip/hip_runtime.h>
#include <hip/hip_bf16.h>

typedef unsigned short u16;
typedef __attribute__((ext_vector_type(8))) short short8;
typedef __attribute__((ext_vector_type(4))) float f32x4;

#define H 8
#define N 384
#define D 32
#define CIN 256
#define HNN (H * N * N)
#define SCALER 0.17677669529663687f
#define EPS 1e-9f

// workspace float offsets
#define PROJ_OFF 0u              // 5*H*N*D = 491520: a,b,c,vj,vk as [5][H][N][D]
#define S_OFF    491520u         // 3*H*N*N: t=0 XT[k][j], t=1 YT[i][k], t=2 Z[i][j]
#define VJT_OFF  4030464u        // H*D*N = 98304: vj transposed [h][d][n]
#define VKT_OFF  4128768u        // H*D*N
#define MX_OFF   4227072u        // 8
#define MY_OFF   4227080u        // H*N
#define MZ_OFF   4230152u        // H*N
#define NUM_OFF  4233224u        // H*N*D
#define DEN_OFF  4331528u        // H*N
#define XBF_OFF  4334600u        // ushort[H*N*N] = 589824 float slots (XT bf16)
#define ZBF_OFF  4924424u        // ushort[H*N*N] (Z bf16)

__device__ inline float bf2f(u16 u) {
    union { unsigned int x; float f; } c; c.x = ((unsigned int)u) << 16; return c.f;
}
__device__ inline u16 f2bf(float f) {
    unsigned int x = __float_as_uint(f);
    return (u16)((x + 0x7FFFu + ((x >> 16) & 1u)) >> 16);
}

// ---------------- K1: projection GEMM  wx[n,m] = sum_k hs[n,k]*W[m,k] ----------------
__global__ __launch_bounds__(256) void proj_kernel(const float* __restrict__ hs,
                                                   const float* __restrict__ W,
                                                   float* __restrict__ proj,
                                                   float* __restrict__ projT) {
    __shared__ float hs_s[64][68];
    __shared__ float w_s[64][68];
    const int tid = threadIdx.x;
    const int tx = tid & 15, ty = tid >> 4;
    const int m0 = blockIdx.x * 64, n0 = blockIdx.y * 64;
    float acc[4][4] = {};
    for (int k0 = 0; k0 < CIN; k0 += 64) {
        __syncthreads();
#pragma unroll
        for (int rep = 0; rep < 4; ++rep) {
            int lin = rep * 1024 + tid * 4;
            int rl = lin >> 6, kl = lin & 63;
            float4 hv = *(const float4*)&hs[(n0 + rl) * CIN + k0 + kl];
            hs_s[kl + 0][rl] = hv.x; hs_s[kl + 1][rl] = hv.y;
            hs_s[kl + 2][rl] = hv.z; hs_s[kl + 3][rl] = hv.w;
            float4 wv = *(const float4*)&W[(m0 + rl) * CIN + k0 + kl];
            w_s[kl + 0][rl] = wv.x; w_s[kl + 1][rl] = wv.y;
            w_s[kl + 2][rl] = wv.z; w_s[kl + 3][rl] = wv.w;
        }
        __syncthreads();
#pragma unroll 16
        for (int kk = 0; kk < 64; ++kk) {
            float4 a4 = *(const float4*)&hs_s[kk][ty * 4];
            float4 b4 = *(const float4*)&w_s[kk][tx * 4];
            float av[4] = {a4.x, a4.y, a4.z, a4.w};
            float bv[4] = {b4.x, b4.y, b4.z, b4.w};
#pragma unroll
            for (int a_ = 0; a_ < 4; ++a_) {
#pragma unroll
                for (int b_ = 0; b_ < 4; ++b_) {
                    acc[a_][b_] = fmaf(av[a_], bv[b_], acc[a_][b_]);
                }
            }
        }
    }
#pragma unroll
    for (int a_ = 0; a_ < 4; ++a_) {
        int n = n0 + ty * 4 + a_;
#pragma unroll
        for (int b_ = 0; b_ < 4; ++b_) {
            int m = m0 + tx * 4 + b_;
            int s = m >> 8, hh = (m >> 5) & 7, d = m & 31;
            proj[s * (H * N * D) + hh * (N * D) + n * D + d] = acc[a_][b_];
            if (s >= 3) projT[(s - 3) * (H * D * N) + hh * (D * N) + d * N + n] = acc[a_][b_];
        }
    }
}

// ---------------- K2: scores ----------------
// t=0: XT[k,j] = c_k . b_j ; t=1: YT[i,k] = a_i . c_k ; t=2: Z[i,j] = a_i . b_j
__global__ __launch_bounds__(256) void scores_kernel(const float* __restrict__ proj,
                                                     float* __restrict__ S) {
    __shared__ float LsT[32][68];
    __shared__ float RsT[32][68];
    const int tid = threadIdx.x, tx = tid & 15, ty = tid >> 4;
    const int r0 = blockIdx.x * 64;
    const int h = blockIdx.y;
    const int t = blockIdx.z;
    const int Lidx = (t == 0) ? 2 : 0;
    const int Ridx = (t == 1) ? 2 : 1;
    const float* Lp = proj + Lidx * (H * N * D) + h * (N * D);
    const float* Rp = proj + Ridx * (H * N * D) + h * (N * D);
    float* Sp = S + t * HNN + h * (N * N);
    {
        int i = tid >> 2, d8 = (tid & 3) * 8;
        float4 v0 = *(const float4*)&Lp[(r0 + i) * D + d8];
        float4 v1 = *(const float4*)&Lp[(r0 + i) * D + d8 + 4];
        LsT[d8 + 0][i] = v0.x; LsT[d8 + 1][i] = v0.y; LsT[d8 + 2][i] = v0.z; LsT[d8 + 3][i] = v0.w;
        LsT[d8 + 4][i] = v1.x; LsT[d8 + 5][i] = v1.y; LsT[d8 + 6][i] = v1.z; LsT[d8 + 7][i] = v1.w;
    }
    for (int c0 = 0; c0 < N; c0 += 64) {
        __syncthreads();
        {
            int i = tid >> 2, d8 = (tid & 3) * 8;
            float4 v0 = *(const float4*)&Rp[(c0 + i) * D + d8];
            float4 v1 = *(const float4*)&Rp[(c0 + i) * D + d8 + 4];
            RsT[d8 + 0][i] = v0.x; RsT[d8 + 1][i] = v0.y; RsT[d8 + 2][i] = v0.z; RsT[d8 + 3][i] = v0.w;
            RsT[d8 + 4][i] = v1.x; RsT[d8 + 5][i] = v1.y; RsT[d8 + 6][i] = v1.z; RsT[d8 + 7][i] = v1.w;
        }
        __syncthreads();
        float acc[4][4] = {};
#pragma unroll
        for (int dd = 0; dd < 32; ++dd) {
            float4 l4 = *(const float4*)&LsT[dd][ty * 4];
            float4 r4 = *(const float4*)&RsT[dd][tx * 4];
            float lv[4] = {l4.x, l4.y, l4.z, l4.w};
            float rv[4] = {r4.x, r4.y, r4.z, r4.w};
#pragma unroll
            for (int a_ = 0; a_ < 4; ++a_) {
#pragma unroll
                for (int b_ = 0; b_ < 4; ++b_) {
                    acc[a_][b_] = fmaf(lv[a_], rv[b_], acc[a_][b_]);
                }
            }
        }
#pragma unroll
        for (int a_ = 0; a_ < 4; ++a_) {
            float4 o;
            o.x = acc[a_][0] * SCALER; o.y = acc[a_][1] * SCALER;
            o.z = acc[a_][2] * SCALER; o.w = acc[a_][3] * SCALER;
            *(float4*)&Sp[(r0 + ty * 4 + a_) * N + c0 + tx * 4] = o;
        }
    }
}

// ---------------- K3: maxima ----------------
__global__ void maxX_kernel(const float* __restrict__ S, float* __restrict__ mX) {
    const int h = blockIdx.x;
    const float* Xp = S + h * (N * N);
    float m = -3.0e38f;
    for (int i = threadIdx.x; i < N * N; i += 256) m = fmaxf(m, Xp[i]);
    __shared__ float red[256];
    red[threadIdx.x] = m;
    __syncthreads();
    for (int s = 128; s > 0; s >>= 1) {
        if (threadIdx.x < s) red[threadIdx.x] = fmaxf(red[threadIdx.x], red[threadIdx.x + s]);
        __syncthreads();
    }
    if (threadIdx.x == 0) mX[h] = red[0];
}

// fused row-max for YT (z=0 -> mY) and Z (z=1 -> mZ)
__global__ void rowmax_kernel(const float* __restrict__ S, float* __restrict__ mY,
                              float* __restrict__ mZ) {
    const int z = blockIdx.z;
    const int h = blockIdx.y;
    const int r = blockIdx.x * 4 + (threadIdx.x >> 6);
    const int lane = threadIdx.x & 63;
    const float* row = S + (1 + z) * HNN + h * (N * N) + r * N;
    float m = -3.0e38f;
    for (int q = lane; q < N; q += 64) m = fmaxf(m, row[q]);
#pragma unroll
    for (int off = 32; off; off >>= 1) m = fmaxf(m, __shfl_down(m, off));
    if (lane == 0) (z == 0 ? mY : mZ)[h * N + r] = m;
}

// ---------------- K4: exp.  t=1 writes f32 in place; t=0/2 write bf16 copies ----------------
__global__ void exp_kernel(float* __restrict__ S, const float* __restrict__ mX,
                           const float* __restrict__ mY, const float* __restrict__ mZ,
                           u16* __restrict__ Xbf, u16* __restrict__ Zbf) {
    int f8 = blockIdx.x * 256 + threadIdx.x;  // 442368 total
    int flat = f8 * 8;
    int t = flat / HNN;
    int rem = flat - t * HNN;
    int h = rem / (N * N);
    int rc = rem - h * (N * N);
    int r = rc / N;
    float m = (t == 0) ? mX[h] : ((t == 1) ? mY[h * N + r] : mZ[h * N + r]);
    float4 v0 = *(float4*)&S[flat];
    float4 v1 = *(float4*)&S[flat + 4];
    float e[8] = {expf(v0.x - m), expf(v0.y - m), expf(v0.z - m), expf(v0.w - m),
                  expf(v1.x - m), expf(v1.y - m), expf(v1.z - m), expf(v1.w - m)};
    if (t == 1) {
        float4 o0 = {e[0], e[1], e[2], e[3]}, o1 = {e[4], e[5], e[6], e[7]};
        *(float4*)&S[flat] = o0;
        *(float4*)&S[flat + 4] = o1;
    } else {
        short8 ov;
#pragma unroll
        for (int q = 0; q < 8; ++q) ov[q] = (short)f2bf(e[q]);
        u16* dst = (t == 0 ? Xbf : Zbf) + h * (N * N) + rc;
        *(short8*)dst = ov;
    }
}

// ---------------- K5: cubic contraction via MFMA bf16, v4 (8 waves, no spill) ----------------
// block (d 0..32, i-tile of 64, h). A = (Z .* vj_d) bf16 in LDS (once).
// B = XT bf16 straight from global to registers (L2-resident).
// Wave w (of 8) owns k in [w*48, w*48+48): acc[fi 0..3][fk 0..2].
// Epilogue (once): Num_i += sum_k M[i,k]*YT[i,k]*vk[k,d]; cross-wave LDS reduce.
__global__ __launch_bounds__(512, 2) void cubic_mfma(
        const u16* __restrict__ Xbf, const u16* __restrict__ Zbf,
        const float* __restrict__ Yt, const float* __restrict__ vjT,
        const float* __restrict__ vkT, float* __restrict__ NumB,
        float* __restrict__ DenB) {
    const int d  = blockIdx.x;        // 0..32 (32 = Den)
    const int i0 = blockIdx.y * 64;
    const int h  = blockIdx.z;
    const int tid = threadIdx.x;
    const int w = tid >> 6, lane = tid & 63;
    const bool den = (d == 32);
    __shared__ u16 A_lds[64 * N];     // [i][j], chunk-swizzled: jchunk ^= (i&7)
    __shared__ float red[8][64];
    const u16* Zh = Zbf + h * (N * N);
    const u16* Xh = Xbf + h * (N * N);
    const float* Yth = Yt + h * (N * N);
    const float* vjd = vjT + h * (D * N) + (den ? 0 : d) * N;
    const float* vkd = vkT + h * (D * N) + (den ? 0 : d) * N;

    // ---- A-prep: 64 rows x 48 chunks(short8); thread -> (row = tid>>3, 6 chunks)
    {
        const int row = tid >> 3;
        const int cb = (tid & 7) * 6;
        const u16* zrow = &Zh[(i0 + row) * N];
        u16* arow = &A_lds[row * N];
        const int sw = (row & 7) << 3;
#pragma unroll
        for (int q = 0; q < 6; ++q) {
            const int jb = (cb + q) * 8;
            short8 zv = *(const short8*)&zrow[jb];
            short8 ov;
            if (den) {
                ov = zv;
            } else {
                float4 vj0 = *(const float4*)&vjd[jb];
                float4 vj1 = *(const float4*)&vjd[jb + 4];
                float vjv[8] = {vj0.x, vj0.y, vj0.z, vj0.w, vj1.x, vj1.y, vj1.z, vj1.w};
#pragma unroll
                for (int e = 0; e < 8; ++e) ov[e] = (short)f2bf(bf2f((u16)zv[e]) * vjv[e]);
            }
            *(short8*)&arow[jb ^ sw] = ov;
        }
    }
    __syncthreads();

    // ---- MFMA main loop: no barriers, k held in accumulators
    f32x4 acc[4][3];
#pragma unroll
    for (int fi = 0; fi < 4; ++fi)
#pragma unroll
        for (int fk = 0; fk < 3; ++fk) acc[fi][fk] = (f32x4){0.f, 0.f, 0.f, 0.f};

    const int l15 = lane & 15;
    const int jc = (lane >> 4) * 8;
    const int sw = (l15 & 7) << 3;    // fi*16 keeps row&7 == lane&7
    const int kwb = w * 48 + l15;

#pragma unroll 2
    for (int js = 0; js < 12; ++js) {
        const int j = js * 32 + jc;
        short8 a[4];
#pragma unroll
        for (int fi = 0; fi < 4; ++fi) {
            a[fi] = *(const short8*)&A_lds[(fi * 16 + l15) * N + (j ^ sw)];
        }
#pragma unroll
        for (int fk = 0; fk < 3; ++fk) {
            const short8 b = *(const short8*)&Xh[(kwb + fk * 16) * N + j];
            acc[0][fk] = __builtin_amdgcn_mfma_f32_16x16x32_bf16(a[0], b, acc[0][fk], 0, 0, 0);
            acc[1][fk] = __builtin_amdgcn_mfma_f32_16x16x32_bf16(a[1], b, acc[1][fk], 0, 0, 0);
            acc[2][fk] = __builtin_amdgcn_mfma_f32_16x16x32_bf16(a[2], b, acc[2][fk], 0, 0, 0);
            acc[3][fk] = __builtin_amdgcn_mfma_f32_16x16x32_bf16(a[3], b, acc[3][fk], 0, 0, 0);
        }
    }

    // ---- epilogue: weight by YT[i,k]*vk[k,d], reduce over k
    float np[4][4];
#pragma unroll
    for (int fi = 0; fi < 4; ++fi)
#pragma unroll
        for (int reg = 0; reg < 4; ++reg) np[fi][reg] = 0.f;

    const int rbase = (lane >> 4) << 2;
#pragma unroll
    for (int fk = 0; fk < 3; ++fk) {
        const int kcol = kwb + fk * 16;
        const float vkv = den ? 1.0f : vkd[kcol];
#pragma unroll
        for (int fi = 0; fi < 4; ++fi) {
#pragma unroll
            for (int reg = 0; reg < 4; ++reg) {
                const int irow = i0 + fi * 16 + rbase + reg;
                const float wgt = Yth[irow * N + kcol] * vkv;
                np[fi][reg] = fmaf(acc[fi][fk][reg], wgt, np[fi][reg]);
            }
        }
    }
#pragma unroll
    for (int fi = 0; fi < 4; ++fi) {
#pragma unroll
        for (int reg = 0; reg < 4; ++reg) {
            float v = np[fi][reg];
            v += __shfl_xor(v, 1); v += __shfl_xor(v, 2);
            v += __shfl_xor(v, 4); v += __shfl_xor(v, 8);
            np[fi][reg] = v;
        }
    }
    if (l15 == 0) {
#pragma unroll
        for (int fi = 0; fi < 4; ++fi)
#pragma unroll
            for (int reg = 0; reg < 4; ++reg)
                red[w][fi * 16 + rbase + reg] = np[fi][reg];
    }
    __syncthreads();
    if (tid < 64) {
        float s = 0.f;
#pragma unroll
        for (int ww = 0; ww < 8; ++ww) s += red[ww][tid];
        if (!den) NumB[h * (N * D) + (i0 + tid) * D + d] = s;
        else      DenB[h * N + i0 + tid] = s;
    }
}

// ---------------- K6: normalize + fp32 output [n, h*D+d] ----------------
__global__ void out_kernel(const float* __restrict__ NumB, const float* __restrict__ DenB,
                           float* __restrict__ out) {
    int idx = blockIdx.x * 256 + threadIdx.x;  // 0..98303
    int n = idx >> 8;
    int ch = idx & 255;
    int hh = ch >> 5, d = ch & 31;
    float v = NumB[hh * (N * D) + n * D + d] / (DenB[hh * N + n] + EPS);
    out[idx] = v;
}

extern "C" void kernel_launch(void* const* d_in, const int* in_sizes, int n_in,
                              void* d_out, int out_size, void* d_ws, size_t ws_size,
                              hipStream_t stream) {
    const float* hs = (const float*)d_in[0];
    const float* W  = (const float*)d_in[1];
    float* ws = (float*)d_ws;
    float* proj  = ws + PROJ_OFF;
    float* S     = ws + S_OFF;
    float* projT = ws + VJT_OFF;    // vj rows, then vk rows at +H*D*N
    float* mX    = ws + MX_OFF;
    float* mY    = ws + MY_OFF;
    float* mZ    = ws + MZ_OFF;
    float* NumB  = ws + NUM_OFF;
    float* DenB  = ws + DEN_OFF;
    u16*   Xbf   = (u16*)(ws + XBF_OFF);
    u16*   Zbf   = (u16*)(ws + ZBF_OFF);
    float* out = (float*)d_out;

    proj_kernel<<<dim3(20, 6), 256, 0, stream>>>(hs, W, proj, projT);
    scores_kernel<<<dim3(6, 8, 3), 256, 0, stream>>>(proj, S);
    maxX_kernel<<<8, 256, 0, stream>>>(S, mX);
    rowmax_kernel<<<dim3(96, 8, 2), 256, 0, stream>>>(S, mY, mZ);
    exp_kernel<<<1728, 256, 0, stream>>>(S, mX, mY, mZ, Xbf, Zbf);
    cubic_mfma<<<dim3(33, 6, 8), 512, 0, stream>>>(Xbf, Zbf, S + HNN, ws + VJT_OFF,
                                                   ws + VKT_OFF, NumB, DenB);
    out_kernel<<<(H * N * D) / 256, 256, 0, stream>>>(NumB, DenB, out);
}

// Round 6
// 223.114 us; speedup vs baseline: 2.5276x; 1.0612x over previous
//
#include <hip/hip_runtime.h>
#include <hip/hip_bf16.h>

typedef unsigned short u16;
typedef __attribute__((ext_vector_type(8))) short short8;
typedef __attribute__((ext_vector_type(4))) float f32x4;

#define H 8
#define N 384
#define D 32
#define CIN 256
#define HNN (H * N * N)
#define SCALER 0.17677669529663687f
#define EPS 1e-9f

// workspace float offsets
#define PROJ_OFF 0u              // 5*H*N*D = 491520: a,b,c,vj,vk as [5][H][N][D]
#define S_OFF    491520u         // 3*H*N*N: t=0 XT[k][j], t=1 YT[i][k], t=2 Z[i][j]
#define VJT_OFF  4030464u        // H*D*N = 98304: vj transposed [h][d][n]
#define VKT_OFF  4128768u        // H*D*N
#define MX_OFF   4227072u        // 8
#define MY_OFF   4227080u        // H*N
#define MZ_OFF   4230152u        // H*N
#define NUM_OFF  4233224u        // H*N*D
#define DEN_OFF  4331528u        // H*N
#define XBF_OFF  4334600u        // ushort[H*N*N] = 589824 float slots (XT bf16)
#define ZBF_OFF  4924424u        // ushort[H*N*N] (Z bf16)

__device__ inline float bf2f(u16 u) {
    union { unsigned int x; float f; } c; c.x = ((unsigned int)u) << 16; return c.f;
}
__device__ inline u16 f2bf(float f) {
    unsigned int x = __float_as_uint(f);
    return (u16)((x + 0x7FFFu + ((x >> 16) & 1u)) >> 16);
}

// ---------------- K1: projection GEMM  wx[n,m] = sum_k hs[n,k]*W[m,k] ----------------
__global__ __launch_bounds__(256) void proj_kernel(const float* __restrict__ hs,
                                                   const float* __restrict__ W,
                                                   float* __restrict__ proj,
                                                   float* __restrict__ projT) {
    __shared__ float hs_s[64][68];
    __shared__ float w_s[64][68];
    const int tid = threadIdx.x;
    const int tx = tid & 15, ty = tid >> 4;
    const int m0 = blockIdx.x * 64, n0 = blockIdx.y * 64;
    float acc[4][4] = {};
    for (int k0 = 0; k0 < CIN; k0 += 64) {
        __syncthreads();
#pragma unroll
        for (int rep = 0; rep < 4; ++rep) {
            int lin = rep * 1024 + tid * 4;
            int rl = lin >> 6, kl = lin & 63;
            float4 hv = *(const float4*)&hs[(n0 + rl) * CIN + k0 + kl];
            hs_s[kl + 0][rl] = hv.x; hs_s[kl + 1][rl] = hv.y;
            hs_s[kl + 2][rl] = hv.z; hs_s[kl + 3][rl] = hv.w;
            float4 wv = *(const float4*)&W[(m0 + rl) * CIN + k0 + kl];
            w_s[kl + 0][rl] = wv.x; w_s[kl + 1][rl] = wv.y;
            w_s[kl + 2][rl] = wv.z; w_s[kl + 3][rl] = wv.w;
        }
        __syncthreads();
#pragma unroll 16
        for (int kk = 0; kk < 64; ++kk) {
            float4 a4 = *(const float4*)&hs_s[kk][ty * 4];
            float4 b4 = *(const float4*)&w_s[kk][tx * 4];
            float av[4] = {a4.x, a4.y, a4.z, a4.w};
            float bv[4] = {b4.x, b4.y, b4.z, b4.w};
#pragma unroll
            for (int a_ = 0; a_ < 4; ++a_) {
#pragma unroll
                for (int b_ = 0; b_ < 4; ++b_) {
                    acc[a_][b_] = fmaf(av[a_], bv[b_], acc[a_][b_]);
                }
            }
        }
    }
#pragma unroll
    for (int a_ = 0; a_ < 4; ++a_) {
        int n = n0 + ty * 4 + a_;
#pragma unroll
        for (int b_ = 0; b_ < 4; ++b_) {
            int m = m0 + tx * 4 + b_;
            int s = m >> 8, hh = (m >> 5) & 7, d = m & 31;
            proj[s * (H * N * D) + hh * (N * D) + n * D + d] = acc[a_][b_];
            if (s >= 3) projT[(s - 3) * (H * D * N) + hh * (D * N) + d * N + n] = acc[a_][b_];
        }
    }
}

// ---------------- K2: scores ----------------
// t=0: XT[k,j] = c_k . b_j ; t=1: YT[i,k] = a_i . c_k ; t=2: Z[i,j] = a_i . b_j
// one 64x64 tile per block
__global__ __launch_bounds__(256) void scores_kernel(const float* __restrict__ proj,
                                                     float* __restrict__ S) {
    __shared__ float LsT[32][68];
    __shared__ float RsT[32][68];
    const int tid = threadIdx.x, tx = tid & 15, ty = tid >> 4;
    const int rt = blockIdx.x % 6, ct = blockIdx.x / 6;
    const int r0 = rt * 64, c0 = ct * 64;
    const int h = blockIdx.y;
    const int t = blockIdx.z;
    const int Lidx = (t == 0) ? 2 : 0;
    const int Ridx = (t == 1) ? 2 : 1;
    const float* Lp = proj + Lidx * (H * N * D) + h * (N * D);
    const float* Rp = proj + Ridx * (H * N * D) + h * (N * D);
    float* Sp = S + t * HNN + h * (N * N);
    {
        int i = tid >> 2, d8 = (tid & 3) * 8;
        float4 v0 = *(const float4*)&Lp[(r0 + i) * D + d8];
        float4 v1 = *(const float4*)&Lp[(r0 + i) * D + d8 + 4];
        LsT[d8 + 0][i] = v0.x; LsT[d8 + 1][i] = v0.y; LsT[d8 + 2][i] = v0.z; LsT[d8 + 3][i] = v0.w;
        LsT[d8 + 4][i] = v1.x; LsT[d8 + 5][i] = v1.y; LsT[d8 + 6][i] = v1.z; LsT[d8 + 7][i] = v1.w;
        float4 w0 = *(const float4*)&Rp[(c0 + i) * D + d8];
        float4 w1 = *(const float4*)&Rp[(c0 + i) * D + d8 + 4];
        RsT[d8 + 0][i] = w0.x; RsT[d8 + 1][i] = w0.y; RsT[d8 + 2][i] = w0.z; RsT[d8 + 3][i] = w0.w;
        RsT[d8 + 4][i] = w1.x; RsT[d8 + 5][i] = w1.y; RsT[d8 + 6][i] = w1.z; RsT[d8 + 7][i] = w1.w;
    }
    __syncthreads();
    float acc[4][4] = {};
#pragma unroll
    for (int dd = 0; dd < 32; ++dd) {
        float4 l4 = *(const float4*)&LsT[dd][ty * 4];
        float4 r4 = *(const float4*)&RsT[dd][tx * 4];
        float lv[4] = {l4.x, l4.y, l4.z, l4.w};
        float rv[4] = {r4.x, r4.y, r4.z, r4.w};
#pragma unroll
        for (int a_ = 0; a_ < 4; ++a_) {
#pragma unroll
            for (int b_ = 0; b_ < 4; ++b_) {
                acc[a_][b_] = fmaf(lv[a_], rv[b_], acc[a_][b_]);
            }
        }
    }
#pragma unroll
    for (int a_ = 0; a_ < 4; ++a_) {
        float4 o;
        o.x = acc[a_][0] * SCALER; o.y = acc[a_][1] * SCALER;
        o.z = acc[a_][2] * SCALER; o.w = acc[a_][3] * SCALER;
        *(float4*)&Sp[(r0 + ty * 4 + a_) * N + c0 + tx * 4] = o;
    }
}

// ---------------- K3: maxima ----------------
__global__ void maxX_kernel(const float* __restrict__ S, float* __restrict__ mX) {
    const int h = blockIdx.x;
    const float* Xp = S + h * (N * N);
    float m = -3.0e38f;
    for (int i = threadIdx.x; i < N * N; i += 256) m = fmaxf(m, Xp[i]);
    __shared__ float red[256];
    red[threadIdx.x] = m;
    __syncthreads();
    for (int s = 128; s > 0; s >>= 1) {
        if (threadIdx.x < s) red[threadIdx.x] = fmaxf(red[threadIdx.x], red[threadIdx.x + s]);
        __syncthreads();
    }
    if (threadIdx.x == 0) mX[h] = red[0];
}

// fused row-max for YT (z=0 -> mY) and Z (z=1 -> mZ)
__global__ void rowmax_kernel(const float* __restrict__ S, float* __restrict__ mY,
                              float* __restrict__ mZ) {
    const int z = blockIdx.z;
    const int h = blockIdx.y;
    const int r = blockIdx.x * 4 + (threadIdx.x >> 6);
    const int lane = threadIdx.x & 63;
    const float* row = S + (1 + z) * HNN + h * (N * N) + r * N;
    float m = -3.0e38f;
    for (int q = lane; q < N; q += 64) m = fmaxf(m, row[q]);
#pragma unroll
    for (int off = 32; off; off >>= 1) m = fmaxf(m, __shfl_down(m, off));
    if (lane == 0) (z == 0 ? mY : mZ)[h * N + r] = m;
}

// ---------------- K4: exp.  t=1 writes f32 in place; t=0/2 write bf16 copies ----------------
__global__ void exp_kernel(float* __restrict__ S, const float* __restrict__ mX,
                           const float* __restrict__ mY, const float* __restrict__ mZ,
                           u16* __restrict__ Xbf, u16* __restrict__ Zbf) {
    int f8 = blockIdx.x * 256 + threadIdx.x;  // 442368 total
    int flat = f8 * 8;
    int t = flat / HNN;
    int rem = flat - t * HNN;
    int h = rem / (N * N);
    int rc = rem - h * (N * N);
    int r = rc / N;
    float m = (t == 0) ? mX[h] : ((t == 1) ? mY[h * N + r] : mZ[h * N + r]);
    float4 v0 = *(float4*)&S[flat];
    float4 v1 = *(float4*)&S[flat + 4];
    float e[8] = {expf(v0.x - m), expf(v0.y - m), expf(v0.z - m), expf(v0.w - m),
                  expf(v1.x - m), expf(v1.y - m), expf(v1.z - m), expf(v1.w - m)};
    if (t == 1) {
        float4 o0 = {e[0], e[1], e[2], e[3]}, o1 = {e[4], e[5], e[6], e[7]};
        *(float4*)&S[flat] = o0;
        *(float4*)&S[flat + 4] = o1;
    } else {
        short8 ov;
#pragma unroll
        for (int q = 0; q < 8; ++q) ov[q] = (short)f2bf(e[q]);
        u16* dst = (t == 0 ? Xbf : Zbf) + h * (N * N) + rc;
        *(short8*)dst = ov;
    }
}

// ---------------- K5: cubic contraction via MFMA bf16, v5 (B-prefetch, XCD swizzle) ----------------
// flattened block id -> (d 0..32, i-tile 0..5, h) with XCD-bijective swizzle:
// wg = (orig%8)*198 + orig/8  => each XCD owns one head's 198 blocks (X L2-private).
// A = (Z .* vj_d) bf16 in LDS (once). B = XT bf16 global->reg, prefetched one js ahead.
// Wave w (of 8) owns k in [w*48, w*48+48): acc[fi 0..3][fk 0..2].
__global__ __launch_bounds__(512, 4) void cubic_mfma(
        const u16* __restrict__ Xbf, const u16* __restrict__ Zbf,
        const float* __restrict__ Yt, const float* __restrict__ vjT,
        const float* __restrict__ vkT, float* __restrict__ NumB,
        float* __restrict__ DenB) {
    const int orig = blockIdx.x;             // 0..1583
    const int wg = (orig & 7) * 198 + (orig >> 3);
    const int d   = wg % 33;
    const int it6 = (wg / 33) % 6;
    const int h   = wg / 198;
    const int i0  = it6 * 64;
    const int tid = threadIdx.x;
    const int w = tid >> 6, lane = tid & 63;
    const bool den = (d == 32);
    __shared__ u16 A_lds[64 * N];     // [i][j], chunk-swizzled: jchunk ^= (i&7)
    __shared__ float red[8][64];
    const u16* Zh = Zbf + h * (N * N);
    const u16* Xh = Xbf + h * (N * N);
    const float* Yth = Yt + h * (N * N);
    const float* vjd = vjT + h * (D * N) + (den ? 0 : d) * N;
    const float* vkd = vkT + h * (D * N) + (den ? 0 : d) * N;

    // ---- A-prep: 64 rows x 48 chunks(short8); thread -> (row = tid>>3, 6 chunks)
    {
        const int row = tid >> 3;
        const int cb = (tid & 7) * 6;
        const u16* zrow = &Zh[(i0 + row) * N];
        u16* arow = &A_lds[row * N];
        const int sw = (row & 7) << 3;
#pragma unroll
        for (int q = 0; q < 6; ++q) {
            const int jb = (cb + q) * 8;
            short8 zv = *(const short8*)&zrow[jb];
            short8 ov;
            if (den) {
                ov = zv;
            } else {
                float4 vj0 = *(const float4*)&vjd[jb];
                float4 vj1 = *(const float4*)&vjd[jb + 4];
                float vjv[8] = {vj0.x, vj0.y, vj0.z, vj0.w, vj1.x, vj1.y, vj1.z, vj1.w};
#pragma unroll
                for (int e = 0; e < 8; ++e) ov[e] = (short)f2bf(bf2f((u16)zv[e]) * vjv[e]);
            }
            *(short8*)&arow[jb ^ sw] = ov;
        }
    }
    __syncthreads();

    // ---- MFMA main loop: no barriers, k held in accumulators; B prefetched 1 js ahead
    f32x4 acc[4][3];
#pragma unroll
    for (int fi = 0; fi < 4; ++fi)
#pragma unroll
        for (int fk = 0; fk < 3; ++fk) acc[fi][fk] = (f32x4){0.f, 0.f, 0.f, 0.f};

    const int l15 = lane & 15;
    const int jc = (lane >> 4) * 8;
    const int sw = (l15 & 7) << 3;    // fi*16 keeps row&7 == lane&7
    const int kwb = w * 48 + l15;
    const u16* Br0 = &Xh[(kwb +  0) * N];
    const u16* Br1 = &Xh[(kwb + 16) * N];
    const u16* Br2 = &Xh[(kwb + 32) * N];

    short8 bA[3], bB[3];
    bA[0] = *(const short8*)&Br0[jc];
    bA[1] = *(const short8*)&Br1[jc];
    bA[2] = *(const short8*)&Br2[jc];

#pragma unroll
    for (int it = 0; it < 6; ++it) {
        const int js0 = it * 2, js1 = it * 2 + 1;
        {   // prefetch js1
            const int j = js1 * 32 + jc;
            bB[0] = *(const short8*)&Br0[j];
            bB[1] = *(const short8*)&Br1[j];
            bB[2] = *(const short8*)&Br2[j];
        }
        {   // compute js0 with bA
            const int j = js0 * 32 + jc;
            short8 a[4];
#pragma unroll
            for (int fi = 0; fi < 4; ++fi)
                a[fi] = *(const short8*)&A_lds[(fi * 16 + l15) * N + (j ^ sw)];
#pragma unroll
            for (int fk = 0; fk < 3; ++fk) {
                acc[0][fk] = __builtin_amdgcn_mfma_f32_16x16x32_bf16(a[0], bA[fk], acc[0][fk], 0, 0, 0);
                acc[1][fk] = __builtin_amdgcn_mfma_f32_16x16x32_bf16(a[1], bA[fk], acc[1][fk], 0, 0, 0);
                acc[2][fk] = __builtin_amdgcn_mfma_f32_16x16x32_bf16(a[2], bA[fk], acc[2][fk], 0, 0, 0);
                acc[3][fk] = __builtin_amdgcn_mfma_f32_16x16x32_bf16(a[3], bA[fk], acc[3][fk], 0, 0, 0);
            }
        }
        if (it < 5) {   // prefetch js0 of next iteration
            const int j = (js1 + 1) * 32 + jc;
            bA[0] = *(const short8*)&Br0[j];
            bA[1] = *(const short8*)&Br1[j];
            bA[2] = *(const short8*)&Br2[j];
        }
        {   // compute js1 with bB
            const int j = js1 * 32 + jc;
            short8 a[4];
#pragma unroll
            for (int fi = 0; fi < 4; ++fi)
                a[fi] = *(const short8*)&A_lds[(fi * 16 + l15) * N + (j ^ sw)];
#pragma unroll
            for (int fk = 0; fk < 3; ++fk) {
                acc[0][fk] = __builtin_amdgcn_mfma_f32_16x16x32_bf16(a[0], bB[fk], acc[0][fk], 0, 0, 0);
                acc[1][fk] = __builtin_amdgcn_mfma_f32_16x16x32_bf16(a[1], bB[fk], acc[1][fk], 0, 0, 0);
                acc[2][fk] = __builtin_amdgcn_mfma_f32_16x16x32_bf16(a[2], bB[fk], acc[2][fk], 0, 0, 0);
                acc[3][fk] = __builtin_amdgcn_mfma_f32_16x16x32_bf16(a[3], bB[fk], acc[3][fk], 0, 0, 0);
            }
        }
    }

    // ---- epilogue: weight by YT[i,k]*vk[k,d], reduce over k
    float np[4][4];
#pragma unroll
    for (int fi = 0; fi < 4; ++fi)
#pragma unroll
        for (int reg = 0; reg < 4; ++reg) np[fi][reg] = 0.f;

    const int rbase = (lane >> 4) << 2;
#pragma unroll
    for (int fk = 0; fk < 3; ++fk) {
        const int kcol = kwb + fk * 16;
        const float vkv = den ? 1.0f : vkd[kcol];
#pragma unroll
        for (int fi = 0; fi < 4; ++fi) {
#pragma unroll
            for (int reg = 0; reg < 4; ++reg) {
                const int irow = i0 + fi * 16 + rbase + reg;
                const float wgt = Yth[irow * N + kcol] * vkv;
                np[fi][reg] = fmaf(acc[fi][fk][reg], wgt, np[fi][reg]);
            }
        }
    }
#pragma unroll
    for (int fi = 0; fi < 4; ++fi) {
#pragma unroll
        for (int reg = 0; reg < 4; ++reg) {
            float v = np[fi][reg];
            v += __shfl_xor(v, 1); v += __shfl_xor(v, 2);
            v += __shfl_xor(v, 4); v += __shfl_xor(v, 8);
            np[fi][reg] = v;
        }
    }
    if (l15 == 0) {
#pragma unroll
        for (int fi = 0; fi < 4; ++fi)
#pragma unroll
            for (int reg = 0; reg < 4; ++reg)
                red[w][fi * 16 + rbase + reg] = np[fi][reg];
    }
    __syncthreads();
    if (tid < 64) {
        float s = 0.f;
#pragma unroll
        for (int ww = 0; ww < 8; ++ww) s += red[ww][tid];
        if (!den) NumB[h * (N * D) + (i0 + tid) * D + d] = s;
        else      DenB[h * N + i0 + tid] = s;
    }
}

// ---------------- K6: normalize + fp32 output [n, h*D+d] ----------------
__global__ void out_kernel(const float* __restrict__ NumB, const float* __restrict__ DenB,
                           float* __restrict__ out) {
    int idx = blockIdx.x * 256 + threadIdx.x;  // 0..98303
    int n = idx >> 8;
    int ch = idx & 255;
    int hh = ch >> 5, d = ch & 31;
    float v = NumB[hh * (N * D) + n * D + d] / (DenB[hh * N + n] + EPS);
    out[idx] = v;
}

extern "C" void kernel_launch(void* const* d_in, const int* in_sizes, int n_in,
                              void* d_out, int out_size, void* d_ws, size_t ws_size,
                              hipStream_t stream) {
    const float* hs = (const float*)d_in[0];
    const float* W  = (const float*)d_in[1];
    float* ws = (float*)d_ws;
    float* proj  = ws + PROJ_OFF;
    float* S     = ws + S_OFF;
    float* projT = ws + VJT_OFF;    // vj rows, then vk rows at +H*D*N
    float* mX    = ws + MX_OFF;
    float* mY    = ws + MY_OFF;
    float* mZ    = ws + MZ_OFF;
    float* NumB  = ws + NUM_OFF;
    float* DenB  = ws + DEN_OFF;
    u16*   Xbf   = (u16*)(ws + XBF_OFF);
    u16*   Zbf   = (u16*)(ws + ZBF_OFF);
    float* out = (float*)d_out;

    proj_kernel<<<dim3(20, 6), 256, 0, stream>>>(hs, W, proj, projT);
    scores_kernel<<<dim3(36, 8, 3), 256, 0, stream>>>(proj, S);
    maxX_kernel<<<8, 256, 0, stream>>>(S, mX);
    rowmax_kernel<<<dim3(96, 8, 2), 256, 0, stream>>>(S, mY, mZ);
    exp_kernel<<<1728, 256, 0, stream>>>(S, mX, mY, mZ, Xbf, Zbf);
    cubic_mfma<<<dim3(1584), 512, 0, stream>>>(Xbf, Zbf, S + HNN, ws + VJT_OFF,
                                               ws + VKT_OFF, NumB, DenB);
    out_kernel<<<(H * N * D) / 256, 256, 0, stream>>>(NumB, DenB, out);
}